// Round 7
// baseline (1898.691 us; speedup 1.0000x reference)
//
#include <hip/hip_runtime.h>
#include <math.h>

#define Bb 16
#define Nn 2048
#define Dd 256
#define Cc 128
#define Kk 20
#define BIG_NEG -1.0e9f

// workspace layout (float offsets)
#define WS_EMIS   0
#define WS_MSC    (WS_EMIS + Bb*Nn*Cc)          // means * inv_var, bf16  [C][D]
#define WS_XQ     (WS_MSC + Cc*Dd)              // sum f^2*inv_var  [B*N]
#define WS_ECHAN  (WS_XQ + Bb*Nn)               // const - 0.5*mq   [C]
#define WS_T      (WS_ECHAN + Cc)               // exp(trans_lp)    [C][C]
#define WS_LEN    (WS_T + Cc*Cc)                // len_lp           [K][C]
#define WS_INIT   (WS_LEN + Kk*Cc)              // init_lp          [C]
#define WS_IVAR   (WS_INIT + Cc)                // 1/cov            [D]

typedef __attribute__((ext_vector_type(8))) short short8;
typedef __attribute__((ext_vector_type(4))) float float4v;
typedef __attribute__((ext_vector_type(2))) float float2v;

__device__ __forceinline__ unsigned short f32_to_bf16(float x) {
  unsigned int u = __builtin_bit_cast(unsigned int, x);
  u = (u + 0x7FFFu + ((u >> 16) & 1u)) >> 16;
  return (unsigned short)u;
}

#define DPP_STEP(x, op, ctrl, rmask)                                          \
  do {                                                                        \
    int _yi = __builtin_amdgcn_update_dpp(                                    \
        __builtin_bit_cast(int, x), __builtin_bit_cast(int, x), ctrl, rmask,  \
        0xF, true);                                                           \
    x = op(x, __builtin_bit_cast(float, _yi));                                \
  } while (0)

__device__ __forceinline__ float dpp_add(float a, float b) { return a + b; }

__device__ __forceinline__ float wave_max64(float x) {
  DPP_STEP(x, fmaxf, 0xB1, 0xF);
  DPP_STEP(x, fmaxf, 0x4E, 0xF);
  DPP_STEP(x, fmaxf, 0x141, 0xF);
  DPP_STEP(x, fmaxf, 0x140, 0xF);
  DPP_STEP(x, fmaxf, 0x142, 0xA);
  DPP_STEP(x, fmaxf, 0x143, 0xC);
  return __builtin_bit_cast(float,
      __builtin_amdgcn_readlane(__builtin_bit_cast(int, x), 63));
}

__device__ __forceinline__ float wave_sum64(float x) {
  DPP_STEP(x, dpp_add, 0xB1, 0xF);
  DPP_STEP(x, dpp_add, 0x4E, 0xF);
  DPP_STEP(x, dpp_add, 0x141, 0xF);
  DPP_STEP(x, dpp_add, 0x140, 0xF);
  DPP_STEP(x, dpp_add, 0x142, 0xA);
  DPP_STEP(x, dpp_add, 0x143, 0xC);
  return __builtin_bit_cast(float,
      __builtin_amdgcn_readlane(__builtin_bit_cast(int, x), 63));
}

// ---------------- small precompute (1 block, 256 threads) ----------------
__global__ void prep_kernel(const float* __restrict__ means,
                            const float* __restrict__ cov,
                            const float* __restrict__ tl,
                            const float* __restrict__ il,
                            const float* __restrict__ plr,
                            float* __restrict__ ws) {
  __shared__ float s_iv[Dd];
  __shared__ float s_red[4];
  __shared__ float s_tlse[Cc];
  int tid = threadIdx.x;

  float cv = cov[tid];
  float iv = 1.0f / cv;
  s_iv[tid] = iv;
  ws[WS_IVAR + tid] = iv;
  float lg = __logf(cv);
  #pragma unroll
  for (int off = 1; off < 64; off <<= 1) lg += __shfl_xor(lg, off, 64);
  if ((tid & 63) == 0) s_red[tid >> 6] = lg;
  __syncthreads();
  float logdet = s_red[0] + s_red[1] + s_red[2] + s_red[3];
  float cconst = -0.5f * ((float)Dd * 1.8378770664093453f + logdet);

  unsigned short* mscb = (unsigned short*)(ws + WS_MSC);
  for (int idx = tid; idx < Cc * Dd; idx += 256) {
    int d = idx & (Dd - 1);
    mscb[idx] = f32_to_bf16(means[idx] * s_iv[d]);
  }
  if (tid < Cc) {
    float acc = 0.0f;
    for (int d = 0; d < Dd; d++) {
      float m = means[tid * Dd + d];
      acc = fmaf(m * m, s_iv[d], acc);
    }
    ws[WS_ECHAN + tid] = cconst - 0.5f * acc;
  }
  for (int idx = tid; idx < Kk * Cc; idx += 256) {
    int L = idx / Cc + 1;
    int c = idx & (Cc - 1);
    float r = plr[c];
    ws[WS_LEN + idx] = (float)L * r - __expf(r) - lgammaf((float)(L + 1));
  }

  __syncthreads();
  float x = (tid < Cc) ? il[tid] : -INFINITY;
  float mx = x;
  #pragma unroll
  for (int off = 1; off < 64; off <<= 1) mx = fmaxf(mx, __shfl_xor(mx, off, 64));
  if ((tid & 63) == 0) s_red[tid >> 6] = mx;
  __syncthreads();
  float M = fmaxf(s_red[0], s_red[1]);
  float se = (tid < Cc) ? __expf(x - M) : 0.0f;
  #pragma unroll
  for (int off = 1; off < 64; off <<= 1) se += __shfl_xor(se, off, 64);
  __syncthreads();
  if ((tid & 63) == 0) s_red[tid >> 6] = se;
  __syncthreads();
  float lse = M + __logf(s_red[0] + s_red[1]);
  if (tid < Cc) ws[WS_INIT + tid] = x - lse;

  if (tid < Cc) {
    int j = tid;
    float m2 = -INFINITY;
    for (int i = 0; i < Cc; i++) if (i != j) m2 = fmaxf(m2, tl[i * Cc + j]);
    float s2 = 0.0f;
    for (int i = 0; i < Cc; i++) if (i != j) s2 += __expf(tl[i * Cc + j] - m2);
    s_tlse[j] = m2 + __logf(s2);
  }
  __syncthreads();
  for (int idx = tid; idx < Cc * Cc; idx += 256) {
    int i = idx / Cc;
    int j = idx & (Cc - 1);
    ws[WS_T + idx] = (i == j) ? 0.0f : __expf(tl[idx] - s_tlse[j]);
  }
}

// ---------------- xq[b,n] = sum_d f^2 * inv_var (one wave per position) ----------------
__global__ void xq_kernel(const float* __restrict__ f, float* __restrict__ ws) {
  int pos = blockIdx.x * 4 + (threadIdx.x >> 6);
  int lane = threadIdx.x & 63;
  const float4 fv = *(const float4*)&f[(size_t)pos * Dd + lane * 4];
  const float4 vv = *(const float4*)&ws[WS_IVAR + lane * 4];
  float a = fv.x * fv.x * vv.x + fv.y * fv.y * vv.y +
            fv.z * fv.z * vv.z + fv.w * fv.w * vv.w;
  #pragma unroll
  for (int off = 1; off < 64; off <<= 1) a += __shfl_xor(a, off, 64);
  if (lane == 0) ws[WS_XQ + pos] = a;
}

// ---------------- emission via MFMA: 32n x 128c per block, 4 waves ----------------
__launch_bounds__(256)
__global__ void emis_mfma_kernel(const float* __restrict__ f, float* __restrict__ ws) {
  const unsigned short* msc = (const unsigned short*)(ws + WS_MSC);
  float* emis = ws + WS_EMIS;
  int tid = threadIdx.x;
  int w = tid >> 6, lane = tid & 63, g = lane >> 4, l16 = lane & 15;
  int b = blockIdx.x >> 6;
  int n0 = (blockIdx.x & 63) << 5;
  int c0 = w << 5;

  const float* fbase = f + (size_t)(b * Nn + n0) * Dd;
  float4v acc[2][2];
  #pragma unroll
  for (int rt = 0; rt < 2; rt++)
    #pragma unroll
    for (int ct = 0; ct < 2; ct++) acc[rt][ct] = (float4v){0.f, 0.f, 0.f, 0.f};

  #pragma unroll
  for (int k0 = 0; k0 < Dd; k0 += 32) {
    int kk = k0 + g * 8;
    short8 afr[2], bfr[2];
    #pragma unroll
    for (int rt = 0; rt < 2; rt++) {
      const float* src = fbase + (size_t)(rt * 16 + l16) * Dd + kk;
      float4 v0 = *(const float4*)src;
      float4 v1 = *(const float4*)(src + 4);
      short8 fr;
      fr[0] = (short)f32_to_bf16(v0.x); fr[1] = (short)f32_to_bf16(v0.y);
      fr[2] = (short)f32_to_bf16(v0.z); fr[3] = (short)f32_to_bf16(v0.w);
      fr[4] = (short)f32_to_bf16(v1.x); fr[5] = (short)f32_to_bf16(v1.y);
      fr[6] = (short)f32_to_bf16(v1.z); fr[7] = (short)f32_to_bf16(v1.w);
      afr[rt] = fr;
    }
    #pragma unroll
    for (int ct = 0; ct < 2; ct++)
      bfr[ct] = *(const short8*)&msc[(size_t)(c0 + ct * 16 + l16) * Dd + kk];
    #pragma unroll
    for (int rt = 0; rt < 2; rt++)
      #pragma unroll
      for (int ct = 0; ct < 2; ct++)
        acc[rt][ct] = __builtin_amdgcn_mfma_f32_16x16x32_bf16(afr[rt], bfr[ct], acc[rt][ct], 0, 0, 0);
  }

  #pragma unroll
  for (int rt = 0; rt < 2; rt++) {
    #pragma unroll
    for (int ct = 0; ct < 2; ct++) {
      int cc = c0 + ct * 16 + l16;
      float ec = ws[WS_ECHAN + cc];
      #pragma unroll
      for (int r = 0; r < 4; r++) {
        int row = rt * 16 + g * 4 + r;
        int nn = n0 + row;
        emis[(size_t)(b * Nn + nn) * Cc + cc] =
            ec - 0.5f * ws[WS_XQ + b * Nn + nn] + acc[rt][ct][r];
      }
    }
  }
}

// ---------------- semi-Markov scan: ONE WAVE, zero barriers, T in LDS ----------------
// Identical algebra to the round-3 PASSING kernel (lane owns channels c0=(l>>4)*32+(l&15),
// c1=c0+16; fresh per-step wave-max normalization; float2 state). Structural change:
// T fragments moved from 128 VGPRs (which forced AGPR/scratch moves at VGPR_Count=192,
// ~128 extra VALU instrs/step -- round 3's hidden cost) into 32 KB of LDS, fragment-linear
// [fid][lane][8] so each (nt,kc) read is one conflict-free ds_read_b128. The 32 T-reads
// per step pipeline under the 32 MFMAs; register footprint drops to ~180 (no spill).
__launch_bounds__(64, 1)
__global__ void scan_kernel(const int* __restrict__ lengths,
                            const float* __restrict__ ws,
                            float* __restrict__ out) {
  __shared__ __align__(16) unsigned short T_lds[32 * 64 * 8];  // 32 KB fragment store
  __shared__ __align__(16) unsigned short p_lds[2][Cc];        // ping-pong p

  int lane = threadIdx.x;
  int g = lane >> 4;
  int l15 = lane & 15;
  int c0 = g * 32 + l15;
  int c1 = c0 + 16;
  int b = blockIdx.x;
  int len_b = lengths[b];
  const float* emis = ws + WS_EMIS + (size_t)b * Nn * Cc;

  // one-time T fragment fill: frag fid = nt*4+kc, lane l holds
  // T[nt*16 + l15][kc*32 + g*8 + j]  (same mapping as the verified register version)
  {
    const float* T = ws + WS_T;
    #pragma unroll
    for (int nt = 0; nt < 8; nt++)
      #pragma unroll
      for (int kc = 0; kc < 4; kc++) {
        const float* src = &T[(size_t)(nt * 16 + l15) * Cc + kc * 32 + g * 8];
        short8 fr;
        #pragma unroll
        for (int j = 0; j < 8; j++) fr[j] = (short)f32_to_bf16(src[j]);
        *(short8*)&T_lds[(size_t)((nt * 4 + kc) * 64 + lane) * 8] = fr;
      }
  }
  // same wave fills and reads; per-use lgkmcnt ordering suffices (no barrier needed)

  float2v elen[Kk];
  #pragma unroll
  for (int k = 0; k < Kk; k++)
    elen[k] = (float2v){__expf(ws[WS_LEN + k * Cc + c0]),
                        __expf(ws[WS_LEN + k * Cc + c1])};

  float2v E[Kk - 1];
  #pragma unroll
  for (int s = 0; s < Kk - 1; s++) E[s] = (float2v){0.0f, 0.0f};

  float2v q = (float2v){__expf(ws[WS_INIT + c0]), __expf(ws[WS_INIT + c1])};
  float2v Stail = (float2v){0.0f, 0.0f};
  float2v cum = (float2v){0.0f, 0.0f};
  float2v Dlt = (float2v){0.0f, 0.0f};
  float2v dcomp = (float2v){0.0f, 0.0f};

  // emission prefetch: e[i] = row (t-1) for step t = tg+i
  float2v e[8], en[8];
  float me[8];
  #pragma unroll
  for (int j = 0; j < 8; j++)
    e[j] = (float2v){emis[(size_t)j * Cc + c0], emis[(size_t)j * Cc + c1]};
  #pragma unroll
  for (int j = 0; j < 8; j++) me[j] = wave_max64(fmaxf(e[j].x, e[j].y));
  float2v ee = (float2v){__expf(e[0].x - me[0]), __expf(e[0].y - me[0])};

  bool done = false;
  for (int tg = 1; tg <= Nn && !done; tg += 8) {
    #pragma unroll
    for (int i = 0; i < 8; i++) {
      int t = tg + i;
      float2v ecur = e[i];
      float2v S = q * elen[0] + Stail;

      if (t == len_b) {
        float ax = cum.x + ecur.x + Dlt.x + __logf(fmaxf(S.x, 1e-37f));
        float ay = cum.y + ecur.y + Dlt.y + __logf(fmaxf(S.y, 1e-37f));
        float Mb = wave_max64(fmaxf(ax, ay));
        float ps = wave_sum64(__expf(ax - Mb) + __expf(ay - Mb));
        if (lane == 0) out[b] = Mb + __logf(ps);
        done = true;
        break;
      }

      float2v v = S * ee;                 // exp(alpha_t - A_{t-1} - me_t), unnormalized
      int buf = t & 1;
      p_lds[buf][c0] = f32_to_bf16(v.x);
      p_lds[buf][c1] = f32_to_bf16(v.y);
      asm volatile("s_waitcnt lgkmcnt(0)" ::: "memory");  // drain the 2 writes only
      short8 pa0 = *(const short8*)&p_lds[buf][g * 8];
      short8 pa1 = *(const short8*)&p_lds[buf][32 + g * 8];
      short8 pa2 = *(const short8*)&p_lds[buf][64 + g * 8];
      short8 pa3 = *(const short8*)&p_lds[buf][96 + g * 8];

      // scale (in the LDS/MFMA latency shadow)
      float wv = fmaxf(wave_max64(fmaxf(v.x, v.y)), 1.0e-30f);
      float r = __builtin_amdgcn_rcpf(wv);

      if (i == 0) {   // group prefetch: rows tg+7 .. tg+14
        #pragma unroll
        for (int j = 0; j < 8; j++) {
          int rr = tg + 7 + j;
          if (rr > Nn - 1) rr = Nn - 1;
          en[j] = (float2v){emis[(size_t)rr * Cc + c0], emis[(size_t)rr * Cc + c1]};
        }
      }

      // matvec: 8 tiles; T fragments streamed from LDS (reads pipeline under MFMAs)
      float4v z = {0.0f, 0.0f, 0.0f, 0.0f};
      float qv[8];
      #pragma unroll
      for (int nt = 0; nt < 8; nt++) {
        const unsigned short* tb = &T_lds[(size_t)(nt * 4 * 64 + lane) * 8];
        short8 t0 = *(const short8*)(tb);
        short8 t1 = *(const short8*)(tb + 64 * 8);
        short8 t2 = *(const short8*)(tb + 2 * 64 * 8);
        short8 t3 = *(const short8*)(tb + 3 * 64 * 8);
        float4v x = __builtin_amdgcn_mfma_f32_16x16x32_bf16(pa1, t1,
                      __builtin_amdgcn_mfma_f32_16x16x32_bf16(pa0, t0, z, 0, 0, 0),
                      0, 0, 0);
        float4v y = __builtin_amdgcn_mfma_f32_16x16x32_bf16(pa3, t3,
                      __builtin_amdgcn_mfma_f32_16x16x32_bf16(pa2, t2, z, 0, 0, 0),
                      0, 0, 0);
        qv[nt] = x[0] + y[0];
      }

      // off-path state update (uses OLD q before reassignment)
      float2v sch = ee * r;               // exp(e_t - dla)
      #pragma unroll
      for (int s = Kk - 2; s >= 1; s--) E[s] = E[s - 1] * sch;
      E[0] = q * sch;

      float2v s0 = E[0] * elen[1];
      float2v s1 = E[1] * elen[2];
      float2v s2 = E[2] * elen[3];
      float2v s3 = E[3] * elen[4];
      s0 = E[4] * elen[5] + s0;   s1 = E[5] * elen[6] + s1;
      s2 = E[6] * elen[7] + s2;   s3 = E[7] * elen[8] + s3;
      s0 = E[8] * elen[9] + s0;   s1 = E[9] * elen[10] + s1;
      s2 = E[10] * elen[11] + s2; s3 = E[11] * elen[12] + s3;
      s0 = E[12] * elen[13] + s0; s1 = E[13] * elen[14] + s1;
      s2 = E[14] * elen[15] + s2; s3 = E[15] * elen[16] + s3;
      s0 = E[16] * elen[17] + s0; s1 = E[17] * elen[18] + s1;
      s2 = E[18] * elen[19] + s2;
      Stail = (s0 + s1) + (s2 + s3);

      // accounting: dla = me + log wv (off the serial chain)
      float dla = me[i] + __logf(wv);
      float2v dd = (float2v){dla, dla} - ecur;
      float2v yk = dd - dcomp;
      float2v t2k = Dlt + yk;
      dcomp = (t2k - Dlt) - yk;
      Dlt = t2k;
      cum += ecur;

      if (i >= 2) me[i - 2] = wave_max64(fmaxf(en[i - 2].x, en[i - 2].y));
      if (i < 7)
        ee = (float2v){__expf(e[i + 1].x - me[i + 1]),
                       __expf(e[i + 1].y - me[i + 1])};

      // in-lane select: q[c0] = tile 2g, q[c1] = tile 2g+1 (col l15)
      float q0 = (g & 2) ? ((g & 1) ? qv[6] : qv[4]) : ((g & 1) ? qv[2] : qv[0]);
      float q1 = (g & 2) ? ((g & 1) ? qv[7] : qv[5]) : ((g & 1) ? qv[3] : qv[1]);
      q = (float2v){q0 * r, q1 * r};      // exp(beta_t - A_t), exactly
    }
    if (!done) {
      me[6] = wave_max64(fmaxf(en[6].x, en[6].y));
      me[7] = wave_max64(fmaxf(en[7].x, en[7].y));
      #pragma unroll
      for (int j = 0; j < 8; j++) e[j] = en[j];
      ee = (float2v){__expf(e[0].x - me[0]), __expf(e[0].y - me[0])};
    }
  }
}

extern "C" void kernel_launch(void* const* d_in, const int* in_sizes, int n_in,
                              void* d_out, int out_size, void* d_ws, size_t ws_size,
                              hipStream_t stream) {
  const float* features = (const float*)d_in[0];
  const int* lengths = (const int*)d_in[1];
  const float* means = (const float*)d_in[2];
  const float* cov = (const float*)d_in[3];
  const float* tl = (const float*)d_in[4];
  const float* il = (const float*)d_in[5];
  const float* plr = (const float*)d_in[6];
  float* out = (float*)d_out;
  float* ws = (float*)d_ws;

  prep_kernel<<<1, 256, 0, stream>>>(means, cov, tl, il, plr, ws);
  xq_kernel<<<(Bb * Nn) / 4, 256, 0, stream>>>(features, ws);
  emis_mfma_kernel<<<Bb * (Nn / 32), 256, 0, stream>>>(features, ws);
  scan_kernel<<<Bb, 64, 0, stream>>>(lengths, ws, out);
}